// Round 5
// baseline (583.109 us; speedup 1.0000x reference)
//
#include <hip/hip_runtime.h>
#include <stdint.h>

#define K_TOT 4096
#define N_TOT 11008
#define M_TOT 256

using bf16x8 = __attribute__((ext_vector_type(8))) short;
using f32x4  = __attribute__((ext_vector_type(4))) float;

#define MFMA(A, B, C) __builtin_amdgcn_mfma_f32_16x16x32_bf16((A), (B), (C), 0, 0, 0)
#define SB() __builtin_amdgcn_sched_barrier(0)

// ---------- prep: fp32 -> bf16 (RNE) for the activation ----------
__global__ void cvt_a_bf16(const float* __restrict__ in, uint32_t* __restrict__ out) {
    int i = blockIdx.x * blockDim.x + threadIdx.x;       // one float4 per thread
    const float4 v = ((const float4*)in)[i];
    uint32_t a = __float_as_uint(v.x), b = __float_as_uint(v.y),
             c = __float_as_uint(v.z), d = __float_as_uint(v.w);
    a += 0x7FFFu + ((a >> 16) & 1u);
    b += 0x7FFFu + ((b >> 16) & 1u);
    c += 0x7FFFu + ((c >> 16) & 1u);
    d += 0x7FFFu + ((d >> 16) & 1u);
    uint2 o;
    o.x = (a >> 16) | (b & 0xFFFF0000u);
    o.y = (c >> 16) | (d & 0xFFFF0000u);
    ((uint2*)out)[i] = o;
}

__device__ __forceinline__ float clamp3(float q, float lo, float hi) {
#if __has_builtin(__builtin_amdgcn_fmed3f)
    return __builtin_amdgcn_fmed3f(q, lo, hi);           // lo<=hi always (0<=zp<=15)
#else
    return fminf(fmaxf(q, lo), hi);
#endif
}

// dequant 8 consecutive-k fp32 -> one bf16x8 MFMA B-fragment.
// clamp(round(w*rs)+zp,0,15)-zp == med3(rint(w*rs), -zp, 15-zp)  (exact: small ints in fp32)
// v_cvt_pk_bf16_f32 = RNE pack of 2 f32, bit-identical to cvt_a_bf16's manual trick.
__device__ __forceinline__ bf16x8 deq8(f32x4 x, f32x4 y, float rs, float lo, float hi, float sc) {
    float d0, d1;
    union { uint32_t u[4]; bf16x8 v; } o;
    d0 = clamp3(rintf(x[0] * rs), lo, hi) * sc;
    d1 = clamp3(rintf(x[1] * rs), lo, hi) * sc;
    asm("v_cvt_pk_bf16_f32 %0, %1, %2" : "=v"(o.u[0]) : "v"(d0), "v"(d1));
    d0 = clamp3(rintf(x[2] * rs), lo, hi) * sc;
    d1 = clamp3(rintf(x[3] * rs), lo, hi) * sc;
    asm("v_cvt_pk_bf16_f32 %0, %1, %2" : "=v"(o.u[1]) : "v"(d0), "v"(d1));
    d0 = clamp3(rintf(y[0] * rs), lo, hi) * sc;
    d1 = clamp3(rintf(y[1] * rs), lo, hi) * sc;
    asm("v_cvt_pk_bf16_f32 %0, %1, %2" : "=v"(o.u[2]) : "v"(d0), "v"(d1));
    d0 = clamp3(rintf(y[2] * rs), lo, hi) * sc;
    d1 = clamp3(rintf(y[3] * rs), lo, hi) * sc;
    asm("v_cvt_pk_bf16_f32 %0, %1, %2" : "=v"(o.u[3]) : "v"(d0), "v"(d1));
    return o.v;
}

// One 64-K step, barrier-free per-wave pipeline; every vmem wait targets only the
// OLDEST outstanding group (vmcnt FIFO), so all loads get >= 1 full iteration in flight:
//   pos1: issue A(s+1)->AN   pos2: issue W(s+2)->WC (freed last iter)
//   pos3: MFMA(s) on AC x b  [waits A(s); W(s+1),A(s+1),W(s+2) survive]
//   pos4: dequant WN=W(s+1) -> b  [waits W(s+1); A(s+1),W(s+2) survive]
#define ITERX(STEP, AC, AN, WC, WN) do {                                        \
    const int _s = (STEP);                                                      \
    const int _ko = _s * 64;                                                    \
    if (_s + 1 < nkt) {                                                         \
        const int _ka = _ko + 64;                                               \
        AN##0 = *(const bf16x8*)(Ap0 + _ka); AN##1 = *(const bf16x8*)(Ap0 + _ka + 32); \
        AN##2 = *(const bf16x8*)(Ap1 + _ka); AN##3 = *(const bf16x8*)(Ap1 + _ka + 32); \
        AN##4 = *(const bf16x8*)(Ap2 + _ka); AN##5 = *(const bf16x8*)(Ap2 + _ka + 32); \
        AN##6 = *(const bf16x8*)(Ap3 + _ka); AN##7 = *(const bf16x8*)(Ap3 + _ka + 32); \
    }                                                                           \
    SB();                                                                       \
    if (_s + 2 < nkt) {                                                         \
        const float* _b0 = Wr0 + _ko + 128;                                     \
        const float* _b1 = Wr1 + _ko + 128;                                     \
        WC##00 = *(const f32x4*)(_b0);      WC##01 = *(const f32x4*)(_b0 + 4);  \
        WC##02 = *(const f32x4*)(_b0 + 32); WC##03 = *(const f32x4*)(_b0 + 36); \
        WC##10 = *(const f32x4*)(_b1);      WC##11 = *(const f32x4*)(_b1 + 4);  \
        WC##12 = *(const f32x4*)(_b1 + 32); WC##13 = *(const f32x4*)(_b1 + 36); \
    }                                                                           \
    SB();                                                                       \
    __builtin_amdgcn_s_setprio(1);                                              \
    acc[0][0] = MFMA(AC##0, b00, acc[0][0]);                                    \
    acc[0][1] = MFMA(AC##0, b10, acc[0][1]);                                    \
    acc[1][0] = MFMA(AC##2, b00, acc[1][0]);                                    \
    acc[1][1] = MFMA(AC##2, b10, acc[1][1]);                                    \
    acc[2][0] = MFMA(AC##4, b00, acc[2][0]);                                    \
    acc[2][1] = MFMA(AC##4, b10, acc[2][1]);                                    \
    acc[3][0] = MFMA(AC##6, b00, acc[3][0]);                                    \
    acc[3][1] = MFMA(AC##6, b10, acc[3][1]);                                    \
    acc[0][0] = MFMA(AC##1, b01, acc[0][0]);                                    \
    acc[0][1] = MFMA(AC##1, b11, acc[0][1]);                                    \
    acc[1][0] = MFMA(AC##3, b01, acc[1][0]);                                    \
    acc[1][1] = MFMA(AC##3, b11, acc[1][1]);                                    \
    acc[2][0] = MFMA(AC##5, b01, acc[2][0]);                                    \
    acc[2][1] = MFMA(AC##5, b11, acc[2][1]);                                    \
    acc[3][0] = MFMA(AC##7, b01, acc[3][0]);                                    \
    acc[3][1] = MFMA(AC##7, b11, acc[3][1]);                                    \
    __builtin_amdgcn_s_setprio(0);                                              \
    SB();                                                                       \
    if (_s + 1 < nkt) {                                                         \
        b00 = deq8(WN##00, WN##01, rs0, lo0, hi0, sc0);                         \
        b01 = deq8(WN##02, WN##03, rs0, lo0, hi0, sc0);                         \
        b10 = deq8(WN##10, WN##11, rs1, lo1, hi1, sc1);                         \
        b11 = deq8(WN##12, WN##13, rs1, lo1, hi1, sc1);                         \
    }                                                                           \
    SB();                                                                       \
} while (0)

// ---------- fused dequant + GEMM over a K-chunk, writes fp32 partials ----------
// Barrier-free, LDS-free. BM=256: one block covers all of M -> each W element is
// fetched from HBM exactly once. 4 waves share W lines via L1 (bare s_barrier
// per iter-pair bounds drift; it attaches NO waitcnt -> pipelines survive).
__global__ __launch_bounds__(256, 3)
void wql_gemm(const uint16_t* __restrict__ A,      // bf16 [256][4096]
              const float* __restrict__ W,         // fp32 [11008][4096]
              const float* __restrict__ scale,
              const float* __restrict__ zero,
              float* __restrict__ P,               // fp32 [KS][256][11008]
              int kloc) {                          // K-chunk length (multiple of 128)
    const int tid  = threadIdx.x;
    const int lane = tid & 63;
    const int wv   = tid >> 6;                     // 4 waves/block
    const int wm   = wv * 64;                      // wave's m-slice
    const int n0   = blockIdx.x * 32;
    const int k0   = blockIdx.y * kloc;
    const int nkt  = kloc >> 6;                    // 64-K steps (even, >= 4)

    const int l15 = lane & 15;
    const int lg8 = (lane >> 4) * 8;

    // per-lane dequant params for the lane's two W rows (n0+l15, n0+16+l15)
    const float sc0 = scale[n0 + l15];
    const float zp0 = zero[n0 + l15];
    const float sc1 = scale[n0 + 16 + l15];
    const float zp1 = zero[n0 + 16 + l15];
    const float rs0 = 1.0f / sc0, lo0 = -zp0, hi0 = 15.0f - zp0;
    const float rs1 = 1.0f / sc1, lo1 = -zp1, hi1 = 15.0f - zp1;

    // W row pointers (lane's k-subgroup baked in)
    const float* Wr0 = W + (size_t)(n0 + l15) * K_TOT + k0 + lg8;
    const float* Wr1 = W + (size_t)(n0 + 16 + l15) * K_TOT + k0 + lg8;

    // A fragment base pointers (direct-from-global; A is 2 MB -> LLC-resident)
    const uint16_t* Ap0 = A + (size_t)(wm +  0 + l15) * K_TOT + k0 + lg8;
    const uint16_t* Ap1 = A + (size_t)(wm + 16 + l15) * K_TOT + k0 + lg8;
    const uint16_t* Ap2 = A + (size_t)(wm + 32 + l15) * K_TOT + k0 + lg8;
    const uint16_t* Ap3 = A + (size_t)(wm + 48 + l15) * K_TOT + k0 + lg8;

    f32x4 acc[4][2];
#pragma unroll
    for (int mi = 0; mi < 4; ++mi)
#pragma unroll
        for (int ni = 0; ni < 2; ++ni)
            acc[mi][ni] = (f32x4){0.f, 0.f, 0.f, 0.f};

    // double-buffered A fragments + raw-W banks; single B-frag set (write-after-last-use)
    bf16x8 aA0, aA1, aA2, aA3, aA4, aA5, aA6, aA7;
    bf16x8 aB0, aB1, aB2, aB3, aB4, aB5, aB6, aB7;
    f32x4  wA00, wA01, wA02, wA03, wA10, wA11, wA12, wA13;
    f32x4  wB00, wB01, wB02, wB03, wB10, wB11, wB12, wB13;
    bf16x8 b00, b01, b10, b11;

    // ---- prologue: A(0)->aA; W(0)->wA; W(1)->wB; dequant W(0)->b ----
    aA0 = *(const bf16x8*)(Ap0); aA1 = *(const bf16x8*)(Ap0 + 32);
    aA2 = *(const bf16x8*)(Ap1); aA3 = *(const bf16x8*)(Ap1 + 32);
    aA4 = *(const bf16x8*)(Ap2); aA5 = *(const bf16x8*)(Ap2 + 32);
    aA6 = *(const bf16x8*)(Ap3); aA7 = *(const bf16x8*)(Ap3 + 32);
    SB();
    wA00 = *(const f32x4*)(Wr0);      wA01 = *(const f32x4*)(Wr0 + 4);
    wA02 = *(const f32x4*)(Wr0 + 32); wA03 = *(const f32x4*)(Wr0 + 36);
    wA10 = *(const f32x4*)(Wr1);      wA11 = *(const f32x4*)(Wr1 + 4);
    wA12 = *(const f32x4*)(Wr1 + 32); wA13 = *(const f32x4*)(Wr1 + 36);
    wB00 = *(const f32x4*)(Wr0 + 64); wB01 = *(const f32x4*)(Wr0 + 68);
    wB02 = *(const f32x4*)(Wr0 + 96); wB03 = *(const f32x4*)(Wr0 + 100);
    wB10 = *(const f32x4*)(Wr1 + 64); wB11 = *(const f32x4*)(Wr1 + 68);
    wB12 = *(const f32x4*)(Wr1 + 96); wB13 = *(const f32x4*)(Wr1 + 100);
    SB();
    b00 = deq8(wA00, wA01, rs0, lo0, hi0, sc0);    // waits W(0) (retires A(0) too - fine)
    b01 = deq8(wA02, wA03, rs0, lo0, hi0, sc0);
    b10 = deq8(wA10, wA11, rs1, lo1, hi1, sc1);
    b11 = deq8(wA12, wA13, rs1, lo1, hi1, sc1);
    SB();

    // ---- main loop: explicit parity, fully static names ----
    for (int s = 0; s < nkt; s += 2) {
        ITERX(s,     aA, aB, wA, wB);
        ITERX(s + 1, aB, aA, wB, wA);
        __builtin_amdgcn_s_barrier();   // bare rendezvous: re-sync 4 waves for L1 W-sharing
    }

    // --- epilogue: store fp32 partial (no bias here) ---
    float* Pb = P + (size_t)blockIdx.y * M_TOT * N_TOT;
    const int colbase = n0 + l15;
    const int rbase = wm + ((lane >> 4) << 2);
#pragma unroll
    for (int mi = 0; mi < 4; ++mi) {
#pragma unroll
        for (int ni = 0; ni < 2; ++ni) {
            const int col = colbase + ni * 16;
#pragma unroll
            for (int r = 0; r < 4; ++r) {
                const int row = rbase + mi * 16 + r;
                Pb[(size_t)row * N_TOT + col] = acc[mi][ni][r];
            }
        }
    }
}

// ---------- reduce KS partial slices + bias -> out (float4 per thread) ----------
__global__ void reduce_bias(const float* __restrict__ P, const float* __restrict__ bias,
                            float* __restrict__ out, int ks) {
    const int i4 = blockIdx.x * blockDim.x + threadIdx.x;   // float4 index
    const size_t tot4 = (size_t)M_TOT * N_TOT / 4;
    const int col = (int)(((size_t)i4 * 4) % N_TOT);        // rows are multiple-of-4 long
    float4 acc = ((const float4*)P)[i4];
    for (int s = 1; s < ks; ++s) {
        const float4 v = ((const float4*)P)[(size_t)s * tot4 + i4];
        acc.x += v.x; acc.y += v.y; acc.z += v.z; acc.w += v.w;
    }
    const float4 b = *(const float4*)(bias + col);
    acc.x += b.x; acc.y += b.y; acc.z += b.z; acc.w += b.w;
    ((float4*)out)[i4] = acc;
}

extern "C" void kernel_launch(void* const* d_in, const int* in_sizes, int n_in,
                              void* d_out, int out_size, void* d_ws, size_t ws_size,
                              hipStream_t stream) {
    const float* inp    = (const float*)d_in[0];
    const float* weight = (const float*)d_in[1];
    const float* bias   = (const float*)d_in[2];
    const float* scale  = (const float*)d_in[3];
    const float* zero   = (const float*)d_in[4];
    // d_in[5] = maxq scalar; fixed at 15 by the reference, hardcoded in dequant.

    const size_t A_BYTES = (size_t)M_TOT * K_TOT * 2;       // 2 MB bf16 activation
    const size_t SLICE   = (size_t)M_TOT * N_TOT * 4;       // 11 MB fp32 partial

    uint32_t* Abf = (uint32_t*)d_ws;
    float* partial;
    int KS;
    if (ws_size >= A_BYTES + 2 * SLICE) { KS = 2; partial = (float*)((char*)d_ws + A_BYTES); }
    else { KS = 1; partial = (float*)d_out; }               // in-place: reduce adds bias only

    cvt_a_bf16<<<dim3((M_TOT * K_TOT / 4) / 256), dim3(256), 0, stream>>>(inp, Abf);

    // grid: (n-tiles, K-chunks) = (344, KS); 256-thread blocks (4 waves), BM=256
    dim3 grid(N_TOT / 32, KS);
    wql_gemm<<<grid, dim3(256), 0, stream>>>((const uint16_t*)Abf, weight, scale, zero,
                                             partial, K_TOT / KS);

    reduce_bias<<<dim3((M_TOT * N_TOT / 4) / 256), dim3(256), 0, stream>>>(
        partial, bias, (float*)d_out, KS);
}

// Round 6
// 497.530 us; speedup vs baseline: 1.1720x; 1.1720x over previous
//
#include <hip/hip_runtime.h>
#include <stdint.h>

#define K_TOT 4096
#define N_TOT 11008
#define M_TOT 256

using bf16x8 = __attribute__((ext_vector_type(8))) short;
using f32x4  = __attribute__((ext_vector_type(4))) float;

#define MFMA(A, B, C) __builtin_amdgcn_mfma_f32_16x16x32_bf16((A), (B), (C), 0, 0, 0)
#define SB() __builtin_amdgcn_sched_barrier(0)

// ---------- prep: fp32 -> bf16 (RNE) for the activation ----------
__global__ void cvt_a_bf16(const float* __restrict__ in, uint32_t* __restrict__ out) {
    int i = blockIdx.x * blockDim.x + threadIdx.x;       // one float4 per thread
    const float4 v = ((const float4*)in)[i];
    uint32_t a = __float_as_uint(v.x), b = __float_as_uint(v.y),
             c = __float_as_uint(v.z), d = __float_as_uint(v.w);
    a += 0x7FFFu + ((a >> 16) & 1u);
    b += 0x7FFFu + ((b >> 16) & 1u);
    c += 0x7FFFu + ((c >> 16) & 1u);
    d += 0x7FFFu + ((d >> 16) & 1u);
    uint2 o;
    o.x = (a >> 16) | (b & 0xFFFF0000u);
    o.y = (c >> 16) | (d & 0xFFFF0000u);
    ((uint2*)out)[i] = o;
}

__device__ __forceinline__ float clamp3(float q, float lo, float hi) {
#if __has_builtin(__builtin_amdgcn_fmed3f)
    return __builtin_amdgcn_fmed3f(q, lo, hi);           // lo<=hi always (0<=zp<=15)
#else
    return fminf(fmaxf(q, lo), hi);
#endif
}

// dequant 8 consecutive-k fp32 -> one bf16x8 MFMA B-fragment.
// clamp(round(w*rs)+zp,0,15)-zp == med3(rint(w*rs), -zp, 15-zp)  (exact: small ints in fp32)
// v_cvt_pk_bf16_f32 = RNE pack of 2 f32, bit-identical to cvt_a_bf16's manual trick.
__device__ __forceinline__ bf16x8 deq8(f32x4 x, f32x4 y, float rs, float lo, float hi, float sc) {
    float d0, d1;
    union { uint32_t u[4]; bf16x8 v; } o;
    d0 = clamp3(rintf(x[0] * rs), lo, hi) * sc;
    d1 = clamp3(rintf(x[1] * rs), lo, hi) * sc;
    asm("v_cvt_pk_bf16_f32 %0, %1, %2" : "=v"(o.u[0]) : "v"(d0), "v"(d1));
    d0 = clamp3(rintf(x[2] * rs), lo, hi) * sc;
    d1 = clamp3(rintf(x[3] * rs), lo, hi) * sc;
    asm("v_cvt_pk_bf16_f32 %0, %1, %2" : "=v"(o.u[1]) : "v"(d0), "v"(d1));
    d0 = clamp3(rintf(y[0] * rs), lo, hi) * sc;
    d1 = clamp3(rintf(y[1] * rs), lo, hi) * sc;
    asm("v_cvt_pk_bf16_f32 %0, %1, %2" : "=v"(o.u[2]) : "v"(d0), "v"(d1));
    d0 = clamp3(rintf(y[2] * rs), lo, hi) * sc;
    d1 = clamp3(rintf(y[3] * rs), lo, hi) * sc;
    asm("v_cvt_pk_bf16_f32 %0, %1, %2" : "=v"(o.u[3]) : "v"(d0), "v"(d1));
    return o.v;
}

// One 64-K step, barrier-free per-wave pipeline (R4 structure, proven spill-free).
// vmem FIFO discipline: A(s) issued first (oldest), W(s+1) after. MFMA's wait for A(s)
// retires only loads older than A(s) — W(s+1) (newer) stays in flight across the MFMA
// block and is consumed by the dequant at the end of the step. TLP (4-5 waves/SIMD)
// hides the in-step A latency.
#define ITER2(STEP, C, N) do {                                                   \
    const int _s = (STEP);                                                       \
    const int _koff = _s * 64;                                                   \
    /* pos1: A(s) fragments (oldest vmem this iter; L2/LLC-resident) */          \
    bf16x8 a0 = *(const bf16x8*)(Ap0 + _koff), a1 = *(const bf16x8*)(Ap0 + _koff + 32), \
           a2 = *(const bf16x8*)(Ap1 + _koff), a3 = *(const bf16x8*)(Ap1 + _koff + 32), \
           a4 = *(const bf16x8*)(Ap2 + _koff), a5 = *(const bf16x8*)(Ap2 + _koff + 32), \
           a6 = *(const bf16x8*)(Ap3 + _koff), a7 = *(const bf16x8*)(Ap3 + _koff + 32); \
    SB();                                                                        \
    /* pos2: raw W(s+1), 256B contiguous per row (full-line efficient) */        \
    if (_s + 1 < nkt) {                                                          \
        const float* _b0 = Wr0 + _koff + 64;                                     \
        const float* _b1 = Wr1 + _koff + 64;                                     \
        w00 = *(const f32x4*)(_b0);      w01 = *(const f32x4*)(_b0 + 4);         \
        w02 = *(const f32x4*)(_b0 + 32); w03 = *(const f32x4*)(_b0 + 36);        \
        w10 = *(const f32x4*)(_b1);      w11 = *(const f32x4*)(_b1 + 4);         \
        w12 = *(const f32x4*)(_b1 + 32); w13 = *(const f32x4*)(_b1 + 36);        \
    }                                                                            \
    SB();                                                                        \
    /* pos3: MFMA(s) — waits A(s); W(s+1) survives */                            \
    __builtin_amdgcn_s_setprio(1);                                               \
    acc[0][0] = MFMA(a0, C##00, acc[0][0]);                                      \
    acc[0][1] = MFMA(a0, C##10, acc[0][1]);                                      \
    acc[1][0] = MFMA(a2, C##00, acc[1][0]);                                      \
    acc[1][1] = MFMA(a2, C##10, acc[1][1]);                                      \
    acc[2][0] = MFMA(a4, C##00, acc[2][0]);                                      \
    acc[2][1] = MFMA(a4, C##10, acc[2][1]);                                      \
    acc[3][0] = MFMA(a6, C##00, acc[3][0]);                                      \
    acc[3][1] = MFMA(a6, C##10, acc[3][1]);                                      \
    acc[0][0] = MFMA(a1, C##01, acc[0][0]);                                      \
    acc[0][1] = MFMA(a1, C##11, acc[0][1]);                                      \
    acc[1][0] = MFMA(a3, C##01, acc[1][0]);                                      \
    acc[1][1] = MFMA(a3, C##11, acc[1][1]);                                      \
    acc[2][0] = MFMA(a5, C##01, acc[2][0]);                                      \
    acc[2][1] = MFMA(a5, C##11, acc[2][1]);                                      \
    acc[3][0] = MFMA(a7, C##01, acc[3][0]);                                      \
    acc[3][1] = MFMA(a7, C##11, acc[3][1]);                                      \
    __builtin_amdgcn_s_setprio(0);                                               \
    SB();                                                                        \
    /* pos4: dequant W(s+1) -> B-frag set N (register-only, feeds next MFMA) */  \
    if (_s + 1 < nkt) {                                                          \
        N##00 = deq8(w00, w01, rs0, lo0, hi0, sc0);                              \
        N##01 = deq8(w02, w03, rs0, lo0, hi0, sc0);                              \
        N##10 = deq8(w10, w11, rs1, lo1, hi1, sc1);                              \
        N##11 = deq8(w12, w13, rs1, lo1, hi1, sc1);                              \
    }                                                                            \
} while (0)

// ---------- fused dequant + GEMM over a K-chunk, writes fp32 partials ----------
// Barrier-free, LDS-free: each wave owns a 64x32 output tile and dequants its own
// B operand in registers. 1D grid + bijective XCD swizzle: the two m-blocks sharing
// a W panel (and neighboring n-tiles) land on the SAME XCD -> W L2-fill ~once.
__global__ __launch_bounds__(128, 4)
void wql_gemm(const uint16_t* __restrict__ A,      // bf16 [256][4096]
              const float* __restrict__ W,         // fp32 [11008][4096]
              const float* __restrict__ scale,
              const float* __restrict__ zero,
              float* __restrict__ P,               // fp32 [KS][256][11008]
              int kloc,                            // K-chunk length (multiple of 128)
              int nwg) {                           // total workgroups (multiple of 8)
    // --- bijective XCD swizzle (dispatch id -> logical id) ---
    // dispatch i goes to XCD i%8; logical = (i%8)*(nwg/8) + i/8 gives each XCD a
    // contiguous logical chunk -> logical-adjacent blocks share an XCD L2.
    const int bid = blockIdx.x;
    const int q = nwg >> 3;
    const int logical = (bid & 7) * q + (bid >> 3);
    const int mb   = logical & 1;                  // m-block (0,1): pair shares W panel
    const int rest = logical >> 1;
    const int nt   = rest % (N_TOT / 32);
    const int kz   = rest / (N_TOT / 32);

    const int tid  = threadIdx.x;
    const int lane = tid & 63;
    const int wv   = tid >> 6;                     // 2 waves/block
    const int wm   = wv * 64;
    const int m0   = mb * 128;
    const int n0   = nt * 32;
    const int k0   = kz * kloc;
    const int nkt  = kloc >> 6;                    // 64-K steps (even)

    const int l15 = lane & 15;
    const int lg8 = (lane >> 4) * 8;

    // per-lane dequant params for the lane's two W rows (n0+l15, n0+16+l15)
    const float sc0 = scale[n0 + l15];
    const float zp0 = zero[n0 + l15];
    const float sc1 = scale[n0 + 16 + l15];
    const float zp1 = zero[n0 + 16 + l15];
    const float rs0 = 1.0f / sc0, lo0 = -zp0, hi0 = 15.0f - zp0;
    const float rs1 = 1.0f / sc1, lo1 = -zp1, hi1 = 15.0f - zp1;

    // W row pointers (lane's k-subgroup baked in)
    const float* Wr0 = W + (size_t)(n0 + l15) * K_TOT + k0 + lg8;
    const float* Wr1 = W + (size_t)(n0 + 16 + l15) * K_TOT + k0 + lg8;

    // A fragment base pointers (direct-from-global, L2/LLC-resident)
    const uint16_t* Ap0 = A + (size_t)(m0 + wm +  0 + l15) * K_TOT + k0 + lg8;
    const uint16_t* Ap1 = A + (size_t)(m0 + wm + 16 + l15) * K_TOT + k0 + lg8;
    const uint16_t* Ap2 = A + (size_t)(m0 + wm + 32 + l15) * K_TOT + k0 + lg8;
    const uint16_t* Ap3 = A + (size_t)(m0 + wm + 48 + l15) * K_TOT + k0 + lg8;

    f32x4 acc[4][2];
#pragma unroll
    for (int mi = 0; mi < 4; ++mi)
#pragma unroll
        for (int ni = 0; ni < 2; ++ni)
            acc[mi][ni] = (f32x4){0.f, 0.f, 0.f, 0.f};

    // raw W register bank (reused every iter) + double-buffered B-frag sets
    f32x4 w00, w01, w02, w03, w10, w11, w12, w13;
    bf16x8 pA00, pA01, pA10, pA11, pB00, pB01, pB10, pB11;

    // ---- prologue: load + dequant W(0) -> pA ----
    {
        w00 = *(const f32x4*)(Wr0);      w01 = *(const f32x4*)(Wr0 + 4);
        w02 = *(const f32x4*)(Wr0 + 32); w03 = *(const f32x4*)(Wr0 + 36);
        w10 = *(const f32x4*)(Wr1);      w11 = *(const f32x4*)(Wr1 + 4);
        w12 = *(const f32x4*)(Wr1 + 32); w13 = *(const f32x4*)(Wr1 + 36);
    }
    pA00 = deq8(w00, w01, rs0, lo0, hi0, sc0);
    pA01 = deq8(w02, w03, rs0, lo0, hi0, sc0);
    pA10 = deq8(w10, w11, rs1, lo1, hi1, sc1);
    pA11 = deq8(w12, w13, rs1, lo1, hi1, sc1);

    // ---- main loop: explicit parity, fully static names ----
    for (int s = 0; s < nkt; s += 2) {
        ITER2(s,     pA, pB);
        ITER2(s + 1, pB, pA);
        __builtin_amdgcn_s_barrier();   // bare rendezvous (no waitcnt): bounds 2-wave
                                        // drift so both waves' W reads share L1/L2
    }

    // --- epilogue: store fp32 partial (no bias here) ---
    float* Pb = P + (size_t)kz * M_TOT * N_TOT;
    const int colbase = n0 + l15;
    const int rbase = m0 + wm + ((lane >> 4) << 2);
#pragma unroll
    for (int mi = 0; mi < 4; ++mi) {
#pragma unroll
        for (int ni = 0; ni < 2; ++ni) {
            const int col = colbase + ni * 16;
#pragma unroll
            for (int r = 0; r < 4; ++r) {
                const int row = rbase + mi * 16 + r;
                Pb[(size_t)row * N_TOT + col] = acc[mi][ni][r];
            }
        }
    }
}

// ---------- reduce KS partial slices + bias -> out (float4 per thread) ----------
__global__ void reduce_bias(const float* __restrict__ P, const float* __restrict__ bias,
                            float* __restrict__ out, int ks) {
    const int i4 = blockIdx.x * blockDim.x + threadIdx.x;   // float4 index
    const size_t tot4 = (size_t)M_TOT * N_TOT / 4;
    const int col = (int)(((size_t)i4 * 4) % N_TOT);        // rows are multiple-of-4 long
    float4 acc = ((const float4*)P)[i4];
    for (int s = 1; s < ks; ++s) {
        const float4 v = ((const float4*)P)[(size_t)s * tot4 + i4];
        acc.x += v.x; acc.y += v.y; acc.z += v.z; acc.w += v.w;
    }
    const float4 b = *(const float4*)(bias + col);
    acc.x += b.x; acc.y += b.y; acc.z += b.z; acc.w += b.w;
    ((float4*)out)[i4] = acc;
}

extern "C" void kernel_launch(void* const* d_in, const int* in_sizes, int n_in,
                              void* d_out, int out_size, void* d_ws, size_t ws_size,
                              hipStream_t stream) {
    const float* inp    = (const float*)d_in[0];
    const float* weight = (const float*)d_in[1];
    const float* bias   = (const float*)d_in[2];
    const float* scale  = (const float*)d_in[3];
    const float* zero   = (const float*)d_in[4];
    // d_in[5] = maxq scalar; fixed at 15 by the reference, hardcoded in dequant.

    const size_t A_BYTES = (size_t)M_TOT * K_TOT * 2;       // 2 MB bf16 activation
    const size_t SLICE   = (size_t)M_TOT * N_TOT * 4;       // 11 MB fp32 partial

    uint32_t* Abf = (uint32_t*)d_ws;
    float* partial;
    int KS;
    if (ws_size >= A_BYTES + 4 * SLICE) { KS = 4; partial = (float*)((char*)d_ws + A_BYTES); }
    else if (ws_size >= A_BYTES + 2 * SLICE) { KS = 2; partial = (float*)((char*)d_ws + A_BYTES); }
    else { KS = 1; partial = (float*)d_out; }               // in-place: reduce adds bias only

    cvt_a_bf16<<<dim3((M_TOT * K_TOT / 4) / 256), dim3(256), 0, stream>>>(inp, Abf);

    // 1D grid with in-kernel XCD swizzle: nwg = (M/128) * (N/32) * KS, multiple of 8
    const int nwg = (M_TOT / 128) * (N_TOT / 32) * KS;      // KS=4 -> 2752
    wql_gemm<<<dim3(nwg), dim3(128), 0, stream>>>((const uint16_t*)Abf, weight, scale, zero,
                                                  partial, K_TOT / KS, nwg);

    reduce_bias<<<dim3((M_TOT * N_TOT / 4) / 256), dim3(256), 0, stream>>>(
        partial, bias, (float*)d_out, KS);
}

// Round 7
// 385.605 us; speedup vs baseline: 1.5122x; 1.2903x over previous
//
#include <hip/hip_runtime.h>
#include <stdint.h>

#define K_TOT 4096
#define N_TOT 11008
#define M_TOT 256

using bf16x8 = __attribute__((ext_vector_type(8))) short;
using f32x4  = __attribute__((ext_vector_type(4))) float;

#define MFMA(A, B, C) __builtin_amdgcn_mfma_f32_16x16x32_bf16((A), (B), (C), 0, 0, 0)
#define SB() __builtin_amdgcn_sched_barrier(0)

// ---------- prep: fp32 -> bf16 (RNE) for the activation ----------
__global__ void cvt_a_bf16(const float* __restrict__ in, uint32_t* __restrict__ out) {
    int i = blockIdx.x * blockDim.x + threadIdx.x;       // one float4 per thread
    const float4 v = ((const float4*)in)[i];
    uint32_t a = __float_as_uint(v.x), b = __float_as_uint(v.y),
             c = __float_as_uint(v.z), d = __float_as_uint(v.w);
    a += 0x7FFFu + ((a >> 16) & 1u);
    b += 0x7FFFu + ((b >> 16) & 1u);
    c += 0x7FFFu + ((c >> 16) & 1u);
    d += 0x7FFFu + ((d >> 16) & 1u);
    uint2 o;
    o.x = (a >> 16) | (b & 0xFFFF0000u);
    o.y = (c >> 16) | (d & 0xFFFF0000u);
    ((uint2*)out)[i] = o;
}

__device__ __forceinline__ float clamp3(float q, float lo, float hi) {
#if __has_builtin(__builtin_amdgcn_fmed3f)
    return __builtin_amdgcn_fmed3f(q, lo, hi);           // lo<=hi always (0<=zp<=15)
#else
    return fminf(fmaxf(q, lo), hi);
#endif
}

// dequant 8 consecutive-k fp32 -> one bf16x8 MFMA B-fragment.
// clamp(round(w*rs)+zp,0,15)-zp == med3(rint(w*rs), -zp, 15-zp)  (exact: small ints in fp32)
// v_cvt_pk_bf16_f32 = RNE pack of 2 f32, bit-identical to cvt_a_bf16's manual trick.
__device__ __forceinline__ bf16x8 deq8(f32x4 x, f32x4 y, float rs, float lo, float hi, float sc) {
    float d0, d1;
    union { uint32_t u[4]; bf16x8 v; } o;
    d0 = clamp3(rintf(x[0] * rs), lo, hi) * sc;
    d1 = clamp3(rintf(x[1] * rs), lo, hi) * sc;
    asm("v_cvt_pk_bf16_f32 %0, %1, %2" : "=v"(o.u[0]) : "v"(d0), "v"(d1));
    d0 = clamp3(rintf(x[2] * rs), lo, hi) * sc;
    d1 = clamp3(rintf(x[3] * rs), lo, hi) * sc;
    asm("v_cvt_pk_bf16_f32 %0, %1, %2" : "=v"(o.u[1]) : "v"(d0), "v"(d1));
    d0 = clamp3(rintf(y[0] * rs), lo, hi) * sc;
    d1 = clamp3(rintf(y[1] * rs), lo, hi) * sc;
    asm("v_cvt_pk_bf16_f32 %0, %1, %2" : "=v"(o.u[2]) : "v"(d0), "v"(d1));
    d0 = clamp3(rintf(y[2] * rs), lo, hi) * sc;
    d1 = clamp3(rintf(y[3] * rs), lo, hi) * sc;
    asm("v_cvt_pk_bf16_f32 %0, %1, %2" : "=v"(o.u[3]) : "v"(d0), "v"(d1));
    return o.v;
}

// One 64-K step, barrier-free per-wave pipeline (R4 structure, proven spill-free at
// launch_bounds(128,3) / VGPR 84).
// vmem FIFO discipline: A(s) issued first (oldest), W(s+1) after. MFMA's wait for A(s)
// retires only loads older than A(s) — W(s+1) (newer) stays in flight across the MFMA
// block and is consumed by the dequant at the end of the step. TLP (~5 waves/SIMD via
// KS=4 grid) hides the in-step A latency.
#define ITER2(STEP, C, N) do {                                                   \
    const int _s = (STEP);                                                       \
    const int _koff = _s * 64;                                                   \
    /* pos1: A(s) fragments (oldest vmem this iter; L2/LLC-resident) */          \
    bf16x8 a0 = *(const bf16x8*)(Ap0 + _koff), a1 = *(const bf16x8*)(Ap0 + _koff + 32), \
           a2 = *(const bf16x8*)(Ap1 + _koff), a3 = *(const bf16x8*)(Ap1 + _koff + 32), \
           a4 = *(const bf16x8*)(Ap2 + _koff), a5 = *(const bf16x8*)(Ap2 + _koff + 32), \
           a6 = *(const bf16x8*)(Ap3 + _koff), a7 = *(const bf16x8*)(Ap3 + _koff + 32); \
    SB();                                                                        \
    /* pos2: raw W(s+1), 256B contiguous per row (full-line efficient) */        \
    if (_s + 1 < nkt) {                                                          \
        const float* _b0 = Wr0 + _koff + 64;                                     \
        const float* _b1 = Wr1 + _koff + 64;                                     \
        w00 = *(const f32x4*)(_b0);      w01 = *(const f32x4*)(_b0 + 4);         \
        w02 = *(const f32x4*)(_b0 + 32); w03 = *(const f32x4*)(_b0 + 36);        \
        w10 = *(const f32x4*)(_b1);      w11 = *(const f32x4*)(_b1 + 4);         \
        w12 = *(const f32x4*)(_b1 + 32); w13 = *(const f32x4*)(_b1 + 36);        \
    }                                                                            \
    SB();                                                                        \
    /* pos3: MFMA(s) — waits A(s); W(s+1) survives */                            \
    __builtin_amdgcn_s_setprio(1);                                               \
    acc[0][0] = MFMA(a0, C##00, acc[0][0]);                                      \
    acc[0][1] = MFMA(a0, C##10, acc[0][1]);                                      \
    acc[1][0] = MFMA(a2, C##00, acc[1][0]);                                      \
    acc[1][1] = MFMA(a2, C##10, acc[1][1]);                                      \
    acc[2][0] = MFMA(a4, C##00, acc[2][0]);                                      \
    acc[2][1] = MFMA(a4, C##10, acc[2][1]);                                      \
    acc[3][0] = MFMA(a6, C##00, acc[3][0]);                                      \
    acc[3][1] = MFMA(a6, C##10, acc[3][1]);                                      \
    acc[0][0] = MFMA(a1, C##01, acc[0][0]);                                      \
    acc[0][1] = MFMA(a1, C##11, acc[0][1]);                                      \
    acc[1][0] = MFMA(a3, C##01, acc[1][0]);                                      \
    acc[1][1] = MFMA(a3, C##11, acc[1][1]);                                      \
    acc[2][0] = MFMA(a5, C##01, acc[2][0]);                                      \
    acc[2][1] = MFMA(a5, C##11, acc[2][1]);                                      \
    acc[3][0] = MFMA(a7, C##01, acc[3][0]);                                      \
    acc[3][1] = MFMA(a7, C##11, acc[3][1]);                                      \
    __builtin_amdgcn_s_setprio(0);                                               \
    SB();                                                                        \
    /* pos4: dequant W(s+1) -> B-frag set N (register-only, feeds next MFMA) */  \
    if (_s + 1 < nkt) {                                                          \
        N##00 = deq8(w00, w01, rs0, lo0, hi0, sc0);                              \
        N##01 = deq8(w02, w03, rs0, lo0, hi0, sc0);                              \
        N##10 = deq8(w10, w11, rs1, lo1, hi1, sc1);                              \
        N##11 = deq8(w12, w13, rs1, lo1, hi1, sc1);                              \
    }                                                                            \
} while (0)

// ---------- fused dequant + GEMM over a K-chunk, writes fp32 partials ----------
// Barrier-free, LDS-free: each wave owns a 64x32 output tile and dequants its own
// B operand in registers. 1D grid + bijective XCD swizzle: the two m-blocks sharing
// a W panel (and neighboring n-tiles) land on the SAME XCD -> W L2-fill ~once.
// launch_bounds(128,3): the (128,4) variant capped VGPRs at 128 and spilled ~235 MB
// of scratch per dispatch (R6); (128,3) holds the pipeline at VGPR 84, zero spill (R4).
__global__ __launch_bounds__(128, 3)
void wql_gemm(const uint16_t* __restrict__ A,      // bf16 [256][4096]
              const float* __restrict__ W,         // fp32 [11008][4096]
              const float* __restrict__ scale,
              const float* __restrict__ zero,
              float* __restrict__ P,               // fp32 [KS][256][11008]
              int kloc,                            // K-chunk length (multiple of 128)
              int nwg) {                           // total workgroups (multiple of 8)
    // --- bijective XCD swizzle (dispatch id -> logical id) ---
    const int bid = blockIdx.x;
    const int q = nwg >> 3;
    const int logical = (bid & 7) * q + (bid >> 3);
    const int mb   = logical & 1;                  // m-block (0,1): pair shares W panel
    const int rest = logical >> 1;
    const int nt   = rest % (N_TOT / 32);
    const int kz   = rest / (N_TOT / 32);

    const int tid  = threadIdx.x;
    const int lane = tid & 63;
    const int wv   = tid >> 6;                     // 2 waves/block
    const int wm   = wv * 64;
    const int m0   = mb * 128;
    const int n0   = nt * 32;
    const int k0   = kz * kloc;
    const int nkt  = kloc >> 6;                    // 64-K steps (even)

    const int l15 = lane & 15;
    const int lg8 = (lane >> 4) * 8;

    // per-lane dequant params for the lane's two W rows (n0+l15, n0+16+l15)
    const float sc0 = scale[n0 + l15];
    const float zp0 = zero[n0 + l15];
    const float sc1 = scale[n0 + 16 + l15];
    const float zp1 = zero[n0 + 16 + l15];
    const float rs0 = 1.0f / sc0, lo0 = -zp0, hi0 = 15.0f - zp0;
    const float rs1 = 1.0f / sc1, lo1 = -zp1, hi1 = 15.0f - zp1;

    // W row pointers (lane's k-subgroup baked in)
    const float* Wr0 = W + (size_t)(n0 + l15) * K_TOT + k0 + lg8;
    const float* Wr1 = W + (size_t)(n0 + 16 + l15) * K_TOT + k0 + lg8;

    // A fragment base pointers (direct-from-global, L2/LLC-resident)
    const uint16_t* Ap0 = A + (size_t)(m0 + wm +  0 + l15) * K_TOT + k0 + lg8;
    const uint16_t* Ap1 = A + (size_t)(m0 + wm + 16 + l15) * K_TOT + k0 + lg8;
    const uint16_t* Ap2 = A + (size_t)(m0 + wm + 32 + l15) * K_TOT + k0 + lg8;
    const uint16_t* Ap3 = A + (size_t)(m0 + wm + 48 + l15) * K_TOT + k0 + lg8;

    f32x4 acc[4][2];
#pragma unroll
    for (int mi = 0; mi < 4; ++mi)
#pragma unroll
        for (int ni = 0; ni < 2; ++ni)
            acc[mi][ni] = (f32x4){0.f, 0.f, 0.f, 0.f};

    // raw W register bank (reused every iter) + double-buffered B-frag sets
    f32x4 w00, w01, w02, w03, w10, w11, w12, w13;
    bf16x8 pA00, pA01, pA10, pA11, pB00, pB01, pB10, pB11;

    // ---- prologue: load + dequant W(0) -> pA ----
    {
        w00 = *(const f32x4*)(Wr0);      w01 = *(const f32x4*)(Wr0 + 4);
        w02 = *(const f32x4*)(Wr0 + 32); w03 = *(const f32x4*)(Wr0 + 36);
        w10 = *(const f32x4*)(Wr1);      w11 = *(const f32x4*)(Wr1 + 4);
        w12 = *(const f32x4*)(Wr1 + 32); w13 = *(const f32x4*)(Wr1 + 36);
    }
    pA00 = deq8(w00, w01, rs0, lo0, hi0, sc0);
    pA01 = deq8(w02, w03, rs0, lo0, hi0, sc0);
    pA10 = deq8(w10, w11, rs1, lo1, hi1, sc1);
    pA11 = deq8(w12, w13, rs1, lo1, hi1, sc1);

    // ---- main loop: explicit parity, fully static names ----
    for (int s = 0; s < nkt; s += 2) {
        ITER2(s,     pA, pB);
        ITER2(s + 1, pB, pA);
        __builtin_amdgcn_s_barrier();   // bare rendezvous (no waitcnt): bounds 2-wave
                                        // drift so both waves' W reads share L1/L2
    }

    // --- epilogue: store fp32 partial (no bias here) ---
    float* Pb = P + (size_t)kz * M_TOT * N_TOT;
    const int colbase = n0 + l15;
    const int rbase = m0 + wm + ((lane >> 4) << 2);
#pragma unroll
    for (int mi = 0; mi < 4; ++mi) {
#pragma unroll
        for (int ni = 0; ni < 2; ++ni) {
            const int col = colbase + ni * 16;
#pragma unroll
            for (int r = 0; r < 4; ++r) {
                const int row = rbase + mi * 16 + r;
                Pb[(size_t)row * N_TOT + col] = acc[mi][ni][r];
            }
        }
    }
}

// ---------- reduce KS partial slices + bias -> out (float4 per thread) ----------
__global__ void reduce_bias(const float* __restrict__ P, const float* __restrict__ bias,
                            float* __restrict__ out, int ks) {
    const int i4 = blockIdx.x * blockDim.x + threadIdx.x;   // float4 index
    const size_t tot4 = (size_t)M_TOT * N_TOT / 4;
    const int col = (int)(((size_t)i4 * 4) % N_TOT);        // rows are multiple-of-4 long
    float4 acc = ((const float4*)P)[i4];
    for (int s = 1; s < ks; ++s) {
        const float4 v = ((const float4*)P)[(size_t)s * tot4 + i4];
        acc.x += v.x; acc.y += v.y; acc.z += v.z; acc.w += v.w;
    }
    const float4 b = *(const float4*)(bias + col);
    acc.x += b.x; acc.y += b.y; acc.z += b.z; acc.w += b.w;
    ((float4*)out)[i4] = acc;
}

extern "C" void kernel_launch(void* const* d_in, const int* in_sizes, int n_in,
                              void* d_out, int out_size, void* d_ws, size_t ws_size,
                              hipStream_t stream) {
    const float* inp    = (const float*)d_in[0];
    const float* weight = (const float*)d_in[1];
    const float* bias   = (const float*)d_in[2];
    const float* scale  = (const float*)d_in[3];
    const float* zero   = (const float*)d_in[4];
    // d_in[5] = maxq scalar; fixed at 15 by the reference, hardcoded in dequant.

    const size_t A_BYTES = (size_t)M_TOT * K_TOT * 2;       // 2 MB bf16 activation
    const size_t SLICE   = (size_t)M_TOT * N_TOT * 4;       // 11 MB fp32 partial

    uint32_t* Abf = (uint32_t*)d_ws;
    float* partial;
    int KS;
    if (ws_size >= A_BYTES + 4 * SLICE) { KS = 4; partial = (float*)((char*)d_ws + A_BYTES); }
    else if (ws_size >= A_BYTES + 2 * SLICE) { KS = 2; partial = (float*)((char*)d_ws + A_BYTES); }
    else { KS = 1; partial = (float*)d_out; }               // in-place: reduce adds bias only

    cvt_a_bf16<<<dim3((M_TOT * K_TOT / 4) / 256), dim3(256), 0, stream>>>(inp, Abf);

    // 1D grid with in-kernel XCD swizzle: nwg = (M/128) * (N/32) * KS, multiple of 8
    const int nwg = (M_TOT / 128) * (N_TOT / 32) * KS;      // KS=4 -> 2752
    wql_gemm<<<dim3(nwg), dim3(128), 0, stream>>>((const uint16_t*)Abf, weight, scale, zero,
                                                  partial, K_TOT / KS, nwg);

    reduce_bias<<<dim3((M_TOT * N_TOT / 4) / 256), dim3(256), 0, stream>>>(
        partial, bias, (float*)d_out, KS);
}